// Round 1
// baseline (514.481 us; speedup 1.0000x reference)
//
#include <hip/hip_runtime.h>
#include <hip/hip_bf16.h>
#include <hip/hip_fp8.h>

#define EMBED 128
#define TSTEPS 128
#define NBATCH 32
#define VDIM 50257
#define VPAD 50304            // 786 groups * 64 cols
#define MROWS 4096            // NBATCH * TSTEPS
#define NGROUPS 786           // VPAD / 64
#define GRIDX 131             // R15: 786 = 131 * 6 exact -> 2096 blocks = 8.2/CU
#define GRIDY 16              // 256-row M slices
#define MAXGRP 6              // groups per x-block (exact, no ragged tail)
#define CONV_N4 ((VDIM * EMBED) / 4)          // 1608224 float4 elements
#define CONV_BLOCKS ((CONV_N4 + 255) / 256)   // 6283

static constexpr float LOG2E = 1.4426950408889634f;
static constexpr float LN2   = 0.6931471805599453f;

__device__ __forceinline__ float fast_exp2(float x) {
#if __has_builtin(__builtin_amdgcn_exp2f)
    return __builtin_amdgcn_exp2f(x);
#else
    return exp2f(x);
#endif
}
__device__ __forceinline__ float fast_log2(float x) {
#if __has_builtin(__builtin_amdgcn_logf)
    return __builtin_amdgcn_logf(x);
#else
    return log2f(x);
#endif
}
__device__ __forceinline__ float fast_rcp(float x) {
#if __has_builtin(__builtin_amdgcn_rcpf)
    return __builtin_amdgcn_rcpf(x);
#else
    return 1.0f / x;
#endif
}
// Branch-free tanh with Newton-refined reciprocal (R12-verified: absmax
// 0.1875 vs libm's 0.125, saved ~8us total by avoiding libm's divergent
// poly/exp paths in the scan).
__device__ __forceinline__ float fast_tanh_nr(float x) {
    x = fminf(20.0f, fmaxf(-20.0f, x));
    float t = fast_exp2((2.0f * LOG2E) * x);    // e^{2x}
    float u = t + 1.0f;
    float r = fast_rcp(u);
    r = r * fmaf(-u, r, 2.0f);                  // Newton: error ~ulp^2
    return (t - 1.0f) * r;
}
__device__ __forceinline__ unsigned short f2bf_raw(float f) {
    __hip_bfloat16 h = __float2bfloat16(f);
    union { __hip_bfloat16 b; unsigned short u; } cvt;
    cvt.b = h;
    return cvt.u;
}
__device__ __forceinline__ float bf_raw2f(unsigned short u) {
    union { unsigned int u; float f; } cvt;
    cvt.u = ((unsigned int)u) << 16;
    return cvt.f;
}
// pack 2 floats -> 2 fp8 e4m3 bytes into the selected half of `old`.
// R13 compile fix: the word-select operand of cvt_pk_fp8 must be an ICE,
// so HI is a template parameter (constant inside the body).
template <bool HI>
__device__ __forceinline__ int pk_fp8(float a, float b, int old) {
#if __has_builtin(__builtin_amdgcn_cvt_pk_fp8_f32)
    return __builtin_amdgcn_cvt_pk_fp8_f32(a, b, old, HI);
#else
    __hip_fp8_e4m3 x(a), y(b);
    int v = (int)(unsigned char)x.__x | ((int)(unsigned char)y.__x << 8);
    return HI ? ((old & 0xffff) | (v << 16)) : ((old & ~0xffff) | v);
#endif
}

// ---------------------------------------------------------------------------
// K0 (fused setup): blocks [0,32) = sequential scan (one batch chain each);
// blocks [32, 32+CONV_BLOCKS) convert Wv fp32 -> fp8 e4m3 (+ zero pad rows),
// build bvs[j] = bv[j]*log2e (pad -> -1e30), and zero S.
//
// Scan = R12-verified structure (e = tid>>1, h = tid&1, one shfl_xor,
// ping-pong z, ONE barrier/step, fast_tanh_nr, 32 KB LDS stash).  The fp32
// summation order ((zc+sA)+sB)+bt is IDENTICAL to rounds 1-12 — the
// recurrence trajectory must not be perturbed (round-4 lesson).  Bulk store
// emits BOTH bf16 (tail's fp32 target dot) and fp8 (gemm A operand).
// NOTE (round-9): no cross-block producer/consumer sync — device-scope
// fences force L2 writeback/invalidate (5.6x regression).
// ---------------------------------------------------------------------------
__global__ __launch_bounds__(256) void setup_kernel(const int* __restrict__ zi,
                                                    const float* __restrict__ latent,
                                                    const float* __restrict__ Wt,
                                                    const float* __restrict__ bt,
                                                    const float* __restrict__ Wv,
                                                    const float* __restrict__ bv,
                                                    unsigned short* __restrict__ zsb,
                                                    unsigned char* __restrict__ zsa8,
                                                    unsigned char* __restrict__ wv8,
                                                    float* __restrict__ bvs,
                                                    float* __restrict__ S) {
    if (blockIdx.x >= NBATCH) {
        const int cb = blockIdx.x - NBATCH;
        if (cb == 0) {                      // zero the S accumulator
#pragma unroll
            for (int i = 0; i < MROWS / 256; i++)
                S[i * 256 + threadIdx.x] = 0.f;
        }
        if (cb == 1) {                      // zero fp8 pad rows of wv8
            const int base  = VDIM * EMBED / 4;          // first pad uint
            const int npad  = (VPAD - VDIM) * EMBED / 4; // 1504 uints
            for (int i = threadIdx.x; i < npad; i += 256)
                reinterpret_cast<unsigned int*>(wv8)[base + i] = 0u;
        }
        const int idx = cb * 256 + threadIdx.x;
        if (idx < VPAD)                     // prescaled, padded bias
            bvs[idx] = (idx < VDIM) ? bv[idx] * LOG2E : -1e30f;
        if (idx < CONV_N4) {
            float4 v = reinterpret_cast<const float4*>(Wv)[idx];
            int p = pk_fp8<false>(v.x, v.y, 0);
            p = pk_fp8<true>(v.z, v.w, p);
            reinterpret_cast<unsigned int*>(wv8)[idx] = (unsigned int)p;
        }
        return;
    }

    // ---- scan path: one block per batch element ----
    __shared__ float zbuf[2][EMBED];
    __shared__ unsigned short zstash[TSTEPS * EMBED];   // 32 KB bf16 stash
    const int b = blockIdx.x;
    const int e = threadIdx.x >> 1;     // output element 0..127
    const int h = threadIdx.x & 1;      // k-half

    // cache Wt[e][h*64 .. h*64+63] in registers (64 VGPRs)
    float4 wrow[16];
    const float4* wt4 = reinterpret_cast<const float4*>(Wt + e * EMBED + h * 64);
#pragma unroll
    for (int i = 0; i < 16; i++) wrow[i] = wt4[i];
    const float bte = bt[e];

    if (h == 0) zbuf[0][e] = latent[zi[b] * EMBED + e];
    __syncthreads();

    int cur = 0;
    for (int t = 0; t < TSTEPS; t++) {
        const float zc = zbuf[cur][e];      // lane pairs broadcast
        if (h == 0)                         // stash pre-update z (bf16 * log2e)
            zstash[t * EMBED + e] = f2bf_raw(zc * LOG2E);

        // half-dot over k in [h*64, h*64+64)
        const float4* z4 = reinterpret_cast<const float4*>(&zbuf[cur][h * 64]);
        float4 acc = {0.f, 0.f, 0.f, 0.f};
#pragma unroll
        for (int i = 0; i < 16; i++) {
            float4 zv = z4[i];
            acc.x += zv.x * wrow[i].x;
            acc.y += zv.y * wrow[i].y;
            acc.z += zv.z * wrow[i].z;
            acc.w += zv.w * wrow[i].w;
        }
        float v = acc.x + acc.y + acc.z + acc.w;
        float p = __shfl_xor(v, 1);         // partner half (same e, other h)
        float sA = h ? p : v;
        float sB = h ? v : p;
        // summation order identical to rounds 1-12 (same dot trajectory)
        float znew = fast_tanh_nr(((zc + sA) + sB) + bte);
        if (h == 0) zbuf[cur ^ 1][e] = znew;
        __syncthreads();                    // lgkmcnt-only drain (no stores)
        cur ^= 1;
    }

    // bulk store: bf16 copy (tail) + fp8 conversion (gemm A), coalesced
    uint4* dstb = reinterpret_cast<uint4*>(zsb + (long)b * TSTEPS * EMBED);
    uint2* dsta = reinterpret_cast<uint2*>(zsa8 + (long)b * TSTEPS * EMBED);
    const uint4* src = reinterpret_cast<const uint4*>(zstash);
    for (int i = threadIdx.x; i < TSTEPS * EMBED / 8; i += 256) {
        uint4 w = src[i];                   // 8 bf16 (z * log2e)
        dstb[i] = w;
        float f0 = bf_raw2f(w.x & 0xffff), f1 = bf_raw2f(w.x >> 16);
        float f2 = bf_raw2f(w.y & 0xffff), f3 = bf_raw2f(w.y >> 16);
        float f4 = bf_raw2f(w.z & 0xffff), f5 = bf_raw2f(w.z >> 16);
        float f6 = bf_raw2f(w.w & 0xffff), f7 = bf_raw2f(w.w >> 16);
        int lo = pk_fp8<false>(f0, f1, 0); lo = pk_fp8<true>(f2, f3, lo);
        int hi = pk_fp8<false>(f4, f5, 0); hi = pk_fp8<true>(f6, f7, hi);
        uint2 o; o.x = (unsigned int)lo; o.y = (unsigned int)hi;
        dsta[i] = o;
    }
}

// ---------------------------------------------------------------------------
// K1: fused GEMM + sum-of-exp2, fp8 operands.
// R15: grid re-split 64x16 -> 131x16.  R14's counters showed Occupancy 30%,
// MfmaUtil 32%, VALUBusy 45%, HBM 1.9% — latency/barrier-bound at 4 blocks/CU
// (grid-limited residency; LDS 17.9KB and 60 VGPR both allow 8 blocks/CU).
// 786 = 131*6 exactly: every block owns 6 groups (no 12-vs-13 ragged tail),
// grid = 2096 blocks ~ 8.2/CU.  __launch_bounds__(256,8) pins VGPR<=64 so the
// doubled residency is guaranteed.  Per-group barrier drains (vmcnt(0) via
// __syncthreads) are now covered by ~2x resident waves (m114 mechanism).
// Structure otherwise R7/R14-verbatim: 4 waves x 64 rows = 256 rows x 6
// groups of 64 N-cols, double-buffered LDS, one barrier per group, LDS bias
// slice, zero-C init, sums = fma(exp2(d), exp2(bias), sums).
// fp8 LDS layout (16B granule, XOR-8 swizzle): phys granule G' = G ^ (r&7);
// fragment ds_read_b64 at r*128 + ((q>>1)^(r&7))*16 + (q&1)*8 -> 16 lanes
// per quad hit distinct bank pairs (free 2-way only).
// A/B fragment (fp8 16x16x32): lane holds [m|n = lane&15][k = quad*8+j],
// j=0..7 packed LSB-first in one i64.  D: row=(lane>>4)*4+r, col=lane&15.
// ---------------------------------------------------------------------------
typedef __attribute__((ext_vector_type(4))) float f32x4;

__global__ __launch_bounds__(256, 8) void gemm_lse_kernel(const unsigned char* __restrict__ zsa8,
                                                          const unsigned char* __restrict__ wv8,
                                                          const float* __restrict__ bvs,
                                                          float* __restrict__ S) {
    __shared__ unsigned char ldsb[2][8192];  // 2 x 8 KB fp8 B tiles
    __shared__ float ldsbias[MAXGRP * 64];   // this block's bias slice (1.5 KB)

    const int lane  = threadIdx.x & 63;
    const int wave  = threadIdx.x >> 6;
    const int col16 = lane & 15;
    const int quad  = lane >> 4;
    const int mbase = blockIdx.y * 256 + wave * 64;

    // group range for this x-block: exact 6 groups each (786 = 131*6)
    const int x  = blockIdx.x;
    const int g0 = x * MAXGRP;
    const int g1 = g0 + MAXGRP;
    const int nbias = MAXGRP * 64;

    // prologue: stage this block's bias slice into LDS
    for (int i = threadIdx.x; i < nbias; i += 256)
        ldsbias[i] = bvs[g0 * 64 + i];

    // A fragments: 4 M-subtiles x 4 K-chunks, one i64 each (32 VGPRs)
    unsigned long long a[4][4];
#pragma unroll
    for (int s = 0; s < 4; s++)
#pragma unroll
        for (int c = 0; c < 4; c++)
            a[s][c] = *reinterpret_cast<const unsigned long long*>(
                zsa8 + (long)(mbase + s * 16 + col16) * EMBED + c * 32 + quad * 8);

    float sums[16];
#pragma unroll
    for (int i = 0; i < 16; i++) sums[i] = 0.f;

    // stage group g's 8 KB fp8 B-tile into ldsb[buf] (XOR-8 swizzle)
    auto stage = [&](int buf, int g) {
#pragma unroll
        for (int j = 0; j < 2; j++) {
            const int rr = (wave * 2 + j) * 8 + (lane >> 3);   // B-row 0..63
            const int G  = (lane & 7) ^ (rr & 7);              // logical granule
            const unsigned char* gp = wv8 + (long)(g * 64 + rr) * EMBED + G * 16;
            __builtin_amdgcn_global_load_lds(
                (const __attribute__((address_space(1))) void*)gp,
                (__attribute__((address_space(3))) void*)&ldsb[buf][(wave * 2 + j) * 1024],
                16, 0, 0);
        }
    };

    int cur = 0;
    stage(0, g0);

    const f32x4 dzero = {0.f, 0.f, 0.f, 0.f};

    for (int g = g0; g < g1; g++) {
        __syncthreads();                     // buf[cur] + bias staged; prev reads done
        if (g + 1 < g1) stage(cur ^ 1, g + 1);

        const float* biasg = &ldsbias[(g - g0) * 64];

#pragma unroll
        for (int c = 0; c < 4; c++) {
            // fragment reads: row r = c*16+col16; byte offset q_abs*8
            // (q_abs = kc*4+quad); phys = ((q_abs>>1)^(r&7))*16 + (q_abs&1)*8
            const unsigned char* rowp = &ldsb[cur][(c * 16 + col16) * 128];
            const int r7 = col16 & 7;
            unsigned long long bf[4];
#pragma unroll
            for (int kc = 0; kc < 4; kc++) {
                const int q_abs = kc * 4 + quad;
                bf[kc] = *reinterpret_cast<const unsigned long long*>(
                    rowp + (((q_abs >> 1) ^ r7) * 16) + ((q_abs & 1) * 8));
            }

            const float eb = fast_exp2(biasg[c * 16 + col16]);  // 0 for pad

            // kc-outer, s-inner: consecutive MFMAs are independent (4 chains)
            f32x4 d[4];
#pragma unroll
            for (int s = 0; s < 4; s++)
                d[s] = __builtin_amdgcn_mfma_f32_16x16x32_fp8_fp8(
                    (long long)a[s][0], (long long)bf[0], dzero, 0, 0, 0);
#pragma unroll
            for (int kc = 1; kc < 4; kc++)
#pragma unroll
                for (int s = 0; s < 4; s++)
                    d[s] = __builtin_amdgcn_mfma_f32_16x16x32_fp8_fp8(
                        (long long)a[s][kc], (long long)bf[kc], d[s], 0, 0, 0);

#pragma unroll
            for (int s = 0; s < 4; s++)
#pragma unroll
                for (int r = 0; r < 4; r++)
                    sums[s * 4 + r] = fmaf(fast_exp2(d[s][r]), eb, sums[s * 4 + r]);
        }
        cur ^= 1;
    }

    // reduce partial sums over the 16 columns, one atomic per row per block
#pragma unroll
    for (int s = 0; s < 4; s++) {
#pragma unroll
        for (int r = 0; r < 4; r++) {
            float v = sums[s * 4 + r];
            v += __shfl_xor(v, 1);
            v += __shfl_xor(v, 2);
            v += __shfl_xor(v, 4);
            v += __shfl_xor(v, 8);
            if (col16 == 0)
                atomicAdd(&S[mbase + s * 16 + quad * 4 + r], v);
        }
    }
}

// ---------------------------------------------------------------------------
// K2: yp[row] = ln2*(dot_scaled - log2(S[row])) + bv[y[row]], where
// dot_scaled = (bf16 zsb row) . (fp32 Wv[y] row)  -- zsb is z*log2e in bf16;
// bf16 quantization adds only ~1e-3 to the target dot.
// One wave per row; lane l handles elements {2l, 2l+1}.
// ---------------------------------------------------------------------------
__global__ __launch_bounds__(256) void tail_kernel(const unsigned short* __restrict__ zsb,
                                                   const float* __restrict__ Wv,
                                                   const float* __restrict__ bv,
                                                   const int* __restrict__ y,
                                                   const float* __restrict__ S,
                                                   float* __restrict__ out) {
    const int row  = blockIdx.x * 4 + (threadIdx.x >> 6);
    const int lane = threadIdx.x & 63;
    const int yv = y[row];
    const ushort2* zr = reinterpret_cast<const ushort2*>(zsb + (long)row * EMBED);
    const float2*  wr = reinterpret_cast<const float2*>(Wv + (long)yv * EMBED);
    ushort2 z2 = zr[lane];
    float2  w2 = wr[lane];
    float v = bf_raw2f(z2.x) * w2.x + bf_raw2f(z2.y) * w2.y;
    v += __shfl_xor(v, 32);
    v += __shfl_xor(v, 16);
    v += __shfl_xor(v, 8);
    v += __shfl_xor(v, 4);
    v += __shfl_xor(v, 2);
    v += __shfl_xor(v, 1);
    if (lane == 0)
        out[row] = LN2 * (v - fast_log2(S[row])) + bv[yv];
}

// ---------------------------------------------------------------------------
extern "C" void kernel_launch(void* const* d_in, const int* in_sizes, int n_in,
                              void* d_out, int out_size, void* d_ws, size_t ws_size,
                              hipStream_t stream) {
    const int*   zi     = (const int*)d_in[0];
    const int*   y      = (const int*)d_in[1];
    const float* latent = (const float*)d_in[2];
    const float* Wt     = (const float*)d_in[3];
    const float* bt     = (const float*)d_in[4];
    const float* Wv     = (const float*)d_in[5];
    const float* bv     = (const float*)d_in[6];
    float* out = (float*)d_out;

    char* ws = (char*)d_ws;
    // workspace layout (~8.3 MB total):
    unsigned short* zsb  = (unsigned short*)ws;                        // 1 MB   @ 0
    unsigned char*  zsa8 = (unsigned char*)(ws + (1u << 20));          // 0.5 MB @ 1M
    float*          S    = (float*)(ws + 1536u * 1024);                // 16 KB  @ 1.5M
    float*          bvs  = (float*)(ws + 1536u * 1024 + (64u << 10));  // 197 KB @ 1.5M+64K
    unsigned char*  wv8  = (unsigned char*)(ws + (2u << 20));          // 6.14MB @ 2M

    setup_kernel<<<NBATCH + CONV_BLOCKS, 256, 0, stream>>>(zi, latent, Wt, bt, Wv, bv,
                                                           zsb, zsa8, wv8, bvs, S);

    gemm_lse_kernel<<<dim3(GRIDX, GRIDY), 256, 0, stream>>>(zsa8, wv8, bvs, S);

    tail_kernel<<<MROWS / 4, 256, 0, stream>>>(zsb, Wv, bv, y, S, out);
}

// Round 2
// 258.732 us; speedup vs baseline: 1.9885x; 1.9885x over previous
//
#include <hip/hip_runtime.h>
#include <hip/hip_bf16.h>
#include <hip/hip_fp8.h>

#define EMBED 128
#define TSTEPS 128
#define NBATCH 32
#define VDIM 50257
#define VPAD 50304            // 786 groups * 64 cols
#define MROWS 4096            // NBATCH * TSTEPS
#define NGROUPS 786           // VPAD / 64
#define GRIDX 131             // R15/R16: 786 = 131 * 6 exact -> 2096 blocks = 8.2/CU
#define GRIDY 16              // 256-row M slices
#define MAXGRP 6              // groups per x-block (exact, no ragged tail)
#define CONV_N4 ((VDIM * EMBED) / 4)          // 1608224 float4 elements
#define CONV_BLOCKS ((CONV_N4 + 255) / 256)   // 6283

static constexpr float LOG2E = 1.4426950408889634f;
static constexpr float LN2   = 0.6931471805599453f;

__device__ __forceinline__ float fast_exp2(float x) {
#if __has_builtin(__builtin_amdgcn_exp2f)
    return __builtin_amdgcn_exp2f(x);
#else
    return exp2f(x);
#endif
}
__device__ __forceinline__ float fast_log2(float x) {
#if __has_builtin(__builtin_amdgcn_logf)
    return __builtin_amdgcn_logf(x);
#else
    return log2f(x);
#endif
}
__device__ __forceinline__ float fast_rcp(float x) {
#if __has_builtin(__builtin_amdgcn_rcpf)
    return __builtin_amdgcn_rcpf(x);
#else
    return 1.0f / x;
#endif
}
// Branch-free tanh with Newton-refined reciprocal (R12-verified: absmax
// 0.1875 vs libm's 0.125, saved ~8us total by avoiding libm's divergent
// poly/exp paths in the scan).
__device__ __forceinline__ float fast_tanh_nr(float x) {
    x = fminf(20.0f, fmaxf(-20.0f, x));
    float t = fast_exp2((2.0f * LOG2E) * x);    // e^{2x}
    float u = t + 1.0f;
    float r = fast_rcp(u);
    r = r * fmaf(-u, r, 2.0f);                  // Newton: error ~ulp^2
    return (t - 1.0f) * r;
}
__device__ __forceinline__ unsigned short f2bf_raw(float f) {
    __hip_bfloat16 h = __float2bfloat16(f);
    union { __hip_bfloat16 b; unsigned short u; } cvt;
    cvt.b = h;
    return cvt.u;
}
__device__ __forceinline__ float bf_raw2f(unsigned short u) {
    union { unsigned int u; float f; } cvt;
    cvt.u = ((unsigned int)u) << 16;
    return cvt.f;
}
// pack 2 floats -> 2 fp8 e4m3 bytes into the selected half of `old`.
// R13 compile fix: the word-select operand of cvt_pk_fp8 must be an ICE,
// so HI is a template parameter (constant inside the body).
template <bool HI>
__device__ __forceinline__ int pk_fp8(float a, float b, int old) {
#if __has_builtin(__builtin_amdgcn_cvt_pk_fp8_f32)
    return __builtin_amdgcn_cvt_pk_fp8_f32(a, b, old, HI);
#else
    __hip_fp8_e4m3 x(a), y(b);
    int v = (int)(unsigned char)x.__x | ((int)(unsigned char)y.__x << 8);
    return HI ? ((old & 0xffff) | (v << 16)) : ((old & ~0xffff) | v);
#endif
}

// ---------------------------------------------------------------------------
// K0 (fused setup): blocks [0,32) = sequential scan (one batch chain each);
// blocks [32, 32+CONV_BLOCKS) convert Wv fp32 -> fp8 e4m3 (+ zero pad rows),
// build bvs[j] = bv[j]*log2e (pad -> -1e30), and zero S.
//
// Scan = R12-verified structure (e = tid>>1, h = tid&1, one shfl_xor,
// ping-pong z, ONE barrier/step, fast_tanh_nr, 32 KB LDS stash).  The fp32
// summation order ((zc+sA)+sB)+bt is IDENTICAL to rounds 1-12 — the
// recurrence trajectory must not be perturbed (round-4 lesson).  Bulk store
// emits BOTH bf16 (tail's fp32 target dot) and fp8 (gemm A operand).
// NOTE (round-9): no cross-block producer/consumer sync — device-scope
// fences force L2 writeback/invalidate (5.6x regression).
// ---------------------------------------------------------------------------
__global__ __launch_bounds__(256) void setup_kernel(const int* __restrict__ zi,
                                                    const float* __restrict__ latent,
                                                    const float* __restrict__ Wt,
                                                    const float* __restrict__ bt,
                                                    const float* __restrict__ Wv,
                                                    const float* __restrict__ bv,
                                                    unsigned short* __restrict__ zsb,
                                                    unsigned char* __restrict__ zsa8,
                                                    unsigned char* __restrict__ wv8,
                                                    float* __restrict__ bvs,
                                                    float* __restrict__ S) {
    if (blockIdx.x >= NBATCH) {
        const int cb = blockIdx.x - NBATCH;
        if (cb == 0) {                      // zero the S accumulator
#pragma unroll
            for (int i = 0; i < MROWS / 256; i++)
                S[i * 256 + threadIdx.x] = 0.f;
        }
        if (cb == 1) {                      // zero fp8 pad rows of wv8
            const int base  = VDIM * EMBED / 4;          // first pad uint
            const int npad  = (VPAD - VDIM) * EMBED / 4; // 1504 uints
            for (int i = threadIdx.x; i < npad; i += 256)
                reinterpret_cast<unsigned int*>(wv8)[base + i] = 0u;
        }
        const int idx = cb * 256 + threadIdx.x;
        if (idx < VPAD)                     // prescaled, padded bias
            bvs[idx] = (idx < VDIM) ? bv[idx] * LOG2E : -1e30f;
        if (idx < CONV_N4) {
            float4 v = reinterpret_cast<const float4*>(Wv)[idx];
            int p = pk_fp8<false>(v.x, v.y, 0);
            p = pk_fp8<true>(v.z, v.w, p);
            reinterpret_cast<unsigned int*>(wv8)[idx] = (unsigned int)p;
        }
        return;
    }

    // ---- scan path: one block per batch element ----
    __shared__ float zbuf[2][EMBED];
    __shared__ unsigned short zstash[TSTEPS * EMBED];   // 32 KB bf16 stash
    const int b = blockIdx.x;
    const int e = threadIdx.x >> 1;     // output element 0..127
    const int h = threadIdx.x & 1;      // k-half

    // cache Wt[e][h*64 .. h*64+63] in registers (64 VGPRs)
    float4 wrow[16];
    const float4* wt4 = reinterpret_cast<const float4*>(Wt + e * EMBED + h * 64);
#pragma unroll
    for (int i = 0; i < 16; i++) wrow[i] = wt4[i];
    const float bte = bt[e];

    if (h == 0) zbuf[0][e] = latent[zi[b] * EMBED + e];
    __syncthreads();

    int cur = 0;
    for (int t = 0; t < TSTEPS; t++) {
        const float zc = zbuf[cur][e];      // lane pairs broadcast
        if (h == 0)                         // stash pre-update z (bf16 * log2e)
            zstash[t * EMBED + e] = f2bf_raw(zc * LOG2E);

        // half-dot over k in [h*64, h*64+64)
        const float4* z4 = reinterpret_cast<const float4*>(&zbuf[cur][h * 64]);
        float4 acc = {0.f, 0.f, 0.f, 0.f};
#pragma unroll
        for (int i = 0; i < 16; i++) {
            float4 zv = z4[i];
            acc.x += zv.x * wrow[i].x;
            acc.y += zv.y * wrow[i].y;
            acc.z += zv.z * wrow[i].z;
            acc.w += zv.w * wrow[i].w;
        }
        float v = acc.x + acc.y + acc.z + acc.w;
        float p = __shfl_xor(v, 1);         // partner half (same e, other h)
        float sA = h ? p : v;
        float sB = h ? v : p;
        // summation order identical to rounds 1-12 (same dot trajectory)
        float znew = fast_tanh_nr(((zc + sA) + sB) + bte);
        if (h == 0) zbuf[cur ^ 1][e] = znew;
        __syncthreads();                    // lgkmcnt-only drain (no stores)
        cur ^= 1;
    }

    // bulk store: bf16 copy (tail) + fp8 conversion (gemm A), coalesced
    uint4* dstb = reinterpret_cast<uint4*>(zsb + (long)b * TSTEPS * EMBED);
    uint2* dsta = reinterpret_cast<uint2*>(zsa8 + (long)b * TSTEPS * EMBED);
    const uint4* src = reinterpret_cast<const uint4*>(zstash);
    for (int i = threadIdx.x; i < TSTEPS * EMBED / 8; i += 256) {
        uint4 w = src[i];                   // 8 bf16 (z * log2e)
        dstb[i] = w;
        float f0 = bf_raw2f(w.x & 0xffff), f1 = bf_raw2f(w.x >> 16);
        float f2 = bf_raw2f(w.y & 0xffff), f3 = bf_raw2f(w.y >> 16);
        float f4 = bf_raw2f(w.z & 0xffff), f5 = bf_raw2f(w.z >> 16);
        float f6 = bf_raw2f(w.w & 0xffff), f7 = bf_raw2f(w.w >> 16);
        int lo = pk_fp8<false>(f0, f1, 0); lo = pk_fp8<true>(f2, f3, lo);
        int hi = pk_fp8<false>(f4, f5, 0); hi = pk_fp8<true>(f6, f7, hi);
        uint2 o; o.x = (unsigned int)lo; o.y = (unsigned int)hi;
        dsta[i] = o;
    }
}

// ---------------------------------------------------------------------------
// K1: fused GEMM + sum-of-exp2, fp8 operands.
// R16: grid 131x16 (exact 6 groups/block, 2096 blocks ~ 8.2/CU) with PLAIN
// __launch_bounds__(256).  R15 post-mortem: the (256,8) hint capped VGPR at
// 64 and the allocator spilled a[4][4]+d[4]+sums to scratch (VGPR_Count 32,
// FETCH 5.3MB->923MB, dur 63->392us).  Natural allocation is ~60 VGPR <= 64,
// so 8 waves/SIMD is already reachable WITHOUT the hint; the grid was the
// only residency limiter, and 131x16 fixes that alone.  R15 also proved the
// residency materializes (Occupancy 30->76%).
// Structure otherwise R7/R14-verbatim: 4 waves x 64 rows = 256 rows x 6
// groups of 64 N-cols, double-buffered LDS, one barrier per group, LDS bias
// slice, zero-C init, sums = fma(exp2(d), exp2(bias), sums).
// fp8 LDS layout (16B granule, XOR-8 swizzle): phys granule G' = G ^ (r&7);
// fragment ds_read_b64 at r*128 + ((q>>1)^(r&7))*16 + (q&1)*8 -> 16 lanes
// per quad hit distinct bank pairs (free 2-way only).
// A/B fragment (fp8 16x16x32): lane holds [m|n = lane&15][k = quad*8+j],
// j=0..7 packed LSB-first in one i64.  D: row=(lane>>4)*4+r, col=lane&15.
// ---------------------------------------------------------------------------
typedef __attribute__((ext_vector_type(4))) float f32x4;

__global__ __launch_bounds__(256) void gemm_lse_kernel(const unsigned char* __restrict__ zsa8,
                                                       const unsigned char* __restrict__ wv8,
                                                       const float* __restrict__ bvs,
                                                       float* __restrict__ S) {
    __shared__ unsigned char ldsb[2][8192];  // 2 x 8 KB fp8 B tiles
    __shared__ float ldsbias[MAXGRP * 64];   // this block's bias slice (1.5 KB)

    const int lane  = threadIdx.x & 63;
    const int wave  = threadIdx.x >> 6;
    const int col16 = lane & 15;
    const int quad  = lane >> 4;
    const int mbase = blockIdx.y * 256 + wave * 64;

    // group range for this x-block: exact 6 groups each (786 = 131*6)
    const int x  = blockIdx.x;
    const int g0 = x * MAXGRP;
    const int g1 = g0 + MAXGRP;
    const int nbias = MAXGRP * 64;

    // prologue: stage this block's bias slice into LDS
    for (int i = threadIdx.x; i < nbias; i += 256)
        ldsbias[i] = bvs[g0 * 64 + i];

    // A fragments: 4 M-subtiles x 4 K-chunks, one i64 each (32 VGPRs)
    unsigned long long a[4][4];
#pragma unroll
    for (int s = 0; s < 4; s++)
#pragma unroll
        for (int c = 0; c < 4; c++)
            a[s][c] = *reinterpret_cast<const unsigned long long*>(
                zsa8 + (long)(mbase + s * 16 + col16) * EMBED + c * 32 + quad * 8);

    float sums[16];
#pragma unroll
    for (int i = 0; i < 16; i++) sums[i] = 0.f;

    // stage group g's 8 KB fp8 B-tile into ldsb[buf] (XOR-8 swizzle)
    auto stage = [&](int buf, int g) {
#pragma unroll
        for (int j = 0; j < 2; j++) {
            const int rr = (wave * 2 + j) * 8 + (lane >> 3);   // B-row 0..63
            const int G  = (lane & 7) ^ (rr & 7);              // logical granule
            const unsigned char* gp = wv8 + (long)(g * 64 + rr) * EMBED + G * 16;
            __builtin_amdgcn_global_load_lds(
                (const __attribute__((address_space(1))) void*)gp,
                (__attribute__((address_space(3))) void*)&ldsb[buf][(wave * 2 + j) * 1024],
                16, 0, 0);
        }
    };

    int cur = 0;
    stage(0, g0);

    const f32x4 dzero = {0.f, 0.f, 0.f, 0.f};

    for (int g = g0; g < g1; g++) {
        __syncthreads();                     // buf[cur] + bias staged; prev reads done
        if (g + 1 < g1) stage(cur ^ 1, g + 1);

        const float* biasg = &ldsbias[(g - g0) * 64];

#pragma unroll
        for (int c = 0; c < 4; c++) {
            // fragment reads: row r = c*16+col16; byte offset q_abs*8
            // (q_abs = kc*4+quad); phys = ((q_abs>>1)^(r&7))*16 + (q_abs&1)*8
            const unsigned char* rowp = &ldsb[cur][(c * 16 + col16) * 128];
            const int r7 = col16 & 7;
            unsigned long long bf[4];
#pragma unroll
            for (int kc = 0; kc < 4; kc++) {
                const int q_abs = kc * 4 + quad;
                bf[kc] = *reinterpret_cast<const unsigned long long*>(
                    rowp + (((q_abs >> 1) ^ r7) * 16) + ((q_abs & 1) * 8));
            }

            const float eb = fast_exp2(biasg[c * 16 + col16]);  // 0 for pad

            // kc-outer, s-inner: consecutive MFMAs are independent (4 chains)
            f32x4 d[4];
#pragma unroll
            for (int s = 0; s < 4; s++)
                d[s] = __builtin_amdgcn_mfma_f32_16x16x32_fp8_fp8(
                    (long long)a[s][0], (long long)bf[0], dzero, 0, 0, 0);
#pragma unroll
            for (int kc = 1; kc < 4; kc++)
#pragma unroll
                for (int s = 0; s < 4; s++)
                    d[s] = __builtin_amdgcn_mfma_f32_16x16x32_fp8_fp8(
                        (long long)a[s][kc], (long long)bf[kc], d[s], 0, 0, 0);

#pragma unroll
            for (int s = 0; s < 4; s++)
#pragma unroll
                for (int r = 0; r < 4; r++)
                    sums[s * 4 + r] = fmaf(fast_exp2(d[s][r]), eb, sums[s * 4 + r]);
        }
        cur ^= 1;
    }

    // reduce partial sums over the 16 columns, one atomic per row per block
#pragma unroll
    for (int s = 0; s < 4; s++) {
#pragma unroll
        for (int r = 0; r < 4; r++) {
            float v = sums[s * 4 + r];
            v += __shfl_xor(v, 1);
            v += __shfl_xor(v, 2);
            v += __shfl_xor(v, 4);
            v += __shfl_xor(v, 8);
            if (col16 == 0)
                atomicAdd(&S[mbase + s * 16 + quad * 4 + r], v);
        }
    }
}

// ---------------------------------------------------------------------------
// K2: yp[row] = ln2*(dot_scaled - log2(S[row])) + bv[y[row]], where
// dot_scaled = (bf16 zsb row) . (fp32 Wv[y] row)  -- zsb is z*log2e in bf16;
// bf16 quantization adds only ~1e-3 to the target dot.
// One wave per row; lane l handles elements {2l, 2l+1}.
// ---------------------------------------------------------------------------
__global__ __launch_bounds__(256) void tail_kernel(const unsigned short* __restrict__ zsb,
                                                   const float* __restrict__ Wv,
                                                   const float* __restrict__ bv,
                                                   const int* __restrict__ y,
                                                   const float* __restrict__ S,
                                                   float* __restrict__ out) {
    const int row  = blockIdx.x * 4 + (threadIdx.x >> 6);
    const int lane = threadIdx.x & 63;
    const int yv = y[row];
    const ushort2* zr = reinterpret_cast<const ushort2*>(zsb + (long)row * EMBED);
    const float2*  wr = reinterpret_cast<const float2*>(Wv + (long)yv * EMBED);
    ushort2 z2 = zr[lane];
    float2  w2 = wr[lane];
    float v = bf_raw2f(z2.x) * w2.x + bf_raw2f(z2.y) * w2.y;
    v += __shfl_xor(v, 32);
    v += __shfl_xor(v, 16);
    v += __shfl_xor(v, 8);
    v += __shfl_xor(v, 4);
    v += __shfl_xor(v, 2);
    v += __shfl_xor(v, 1);
    if (lane == 0)
        out[row] = LN2 * (v - fast_log2(S[row])) + bv[yv];
}

// ---------------------------------------------------------------------------
extern "C" void kernel_launch(void* const* d_in, const int* in_sizes, int n_in,
                              void* d_out, int out_size, void* d_ws, size_t ws_size,
                              hipStream_t stream) {
    const int*   zi     = (const int*)d_in[0];
    const int*   y      = (const int*)d_in[1];
    const float* latent = (const float*)d_in[2];
    const float* Wt     = (const float*)d_in[3];
    const float* bt     = (const float*)d_in[4];
    const float* Wv     = (const float*)d_in[5];
    const float* bv     = (const float*)d_in[6];
    float* out = (float*)d_out;

    char* ws = (char*)d_ws;
    // workspace layout (~8.3 MB total):
    unsigned short* zsb  = (unsigned short*)ws;                        // 1 MB   @ 0
    unsigned char*  zsa8 = (unsigned char*)(ws + (1u << 20));          // 0.5 MB @ 1M
    float*          S    = (float*)(ws + 1536u * 1024);                // 16 KB  @ 1.5M
    float*          bvs  = (float*)(ws + 1536u * 1024 + (64u << 10));  // 197 KB @ 1.5M+64K
    unsigned char*  wv8  = (unsigned char*)(ws + (2u << 20));          // 6.14MB @ 2M

    setup_kernel<<<NBATCH + CONV_BLOCKS, 256, 0, stream>>>(zi, latent, Wt, bt, Wv, bv,
                                                           zsb, zsa8, wv8, bvs, S);

    gemm_lse_kernel<<<dim3(GRIDX, GRIDY), 256, 0, stream>>>(zsa8, wv8, bvs, S);

    tail_kernel<<<MROWS / 4, 256, 0, stream>>>(zsb, Wv, bv, y, S, out);
}

// Round 3
// 209.789 us; speedup vs baseline: 2.4524x; 1.2333x over previous
//
#include <hip/hip_runtime.h>
#include <hip/hip_bf16.h>
#include <hip/hip_fp8.h>

#define EMBED 128
#define TSTEPS 128
#define NBATCH 32
#define VDIM 50257
#define VPAD 50304            // 786 groups * 64 cols
#define MROWS 4096            // NBATCH * TSTEPS
#define NGROUPS 786           // VPAD / 64
#define GRIDX 131             // 786 = 131 * 6 exact -> 2096 blocks = 8.2/CU
#define GRIDY 16              // 256-row M slices
#define MAXGRP 6              // groups per x-block (exact, no ragged tail)
#define CONV_N4 ((VDIM * EMBED) / 4)          // 1608224 float4 elements
#define CONV_BLOCKS ((CONV_N4 + 255) / 256)   // 6283

static constexpr float LOG2E = 1.4426950408889634f;
static constexpr float LN2   = 0.6931471805599453f;

__device__ __forceinline__ float fast_exp2(float x) {
#if __has_builtin(__builtin_amdgcn_exp2f)
    return __builtin_amdgcn_exp2f(x);
#else
    return exp2f(x);
#endif
}
__device__ __forceinline__ float fast_log2(float x) {
#if __has_builtin(__builtin_amdgcn_logf)
    return __builtin_amdgcn_logf(x);
#else
    return log2f(x);
#endif
}
__device__ __forceinline__ float fast_rcp(float x) {
#if __has_builtin(__builtin_amdgcn_rcpf)
    return __builtin_amdgcn_rcpf(x);
#else
    return 1.0f / x;
#endif
}
// Branch-free tanh with Newton-refined reciprocal (R12-verified: absmax
// 0.1875 vs libm's 0.125, saved ~8us total by avoiding libm's divergent
// poly/exp paths in the scan).
__device__ __forceinline__ float fast_tanh_nr(float x) {
    x = fminf(20.0f, fmaxf(-20.0f, x));
    float t = fast_exp2((2.0f * LOG2E) * x);    // e^{2x}
    float u = t + 1.0f;
    float r = fast_rcp(u);
    r = r * fmaf(-u, r, 2.0f);                  // Newton: error ~ulp^2
    return (t - 1.0f) * r;
}
__device__ __forceinline__ unsigned short f2bf_raw(float f) {
    __hip_bfloat16 h = __float2bfloat16(f);
    union { __hip_bfloat16 b; unsigned short u; } cvt;
    cvt.b = h;
    return cvt.u;
}
__device__ __forceinline__ float bf_raw2f(unsigned short u) {
    union { unsigned int u; float f; } cvt;
    cvt.u = ((unsigned int)u) << 16;
    return cvt.f;
}
// pack 2 floats -> 2 fp8 e4m3 bytes into the selected half of `old`.
// R13 compile fix: the word-select operand of cvt_pk_fp8 must be an ICE,
// so HI is a template parameter (constant inside the body).
template <bool HI>
__device__ __forceinline__ int pk_fp8(float a, float b, int old) {
#if __has_builtin(__builtin_amdgcn_cvt_pk_fp8_f32)
    return __builtin_amdgcn_cvt_pk_fp8_f32(a, b, old, HI);
#else
    __hip_fp8_e4m3 x(a), y(b);
    int v = (int)(unsigned char)x.__x | ((int)(unsigned char)y.__x << 8);
    return HI ? ((old & 0xffff) | (v << 16)) : ((old & ~0xffff) | v);
#endif
}

// ---------------------------------------------------------------------------
// K0 (fused setup): blocks [0,32) = sequential scan (one batch chain each);
// blocks [32, 32+CONV_BLOCKS) convert Wv fp32 -> fp8 e4m3 (+ zero pad rows),
// build bvs[j] = bv[j]*log2e (pad -> -1e30), and zero S.
//
// Scan = R12-verified structure (e = tid>>1, h = tid&1, one shfl_xor,
// ping-pong z, ONE barrier/step, fast_tanh_nr, 32 KB LDS stash).  The fp32
// summation order ((zc+sA)+sB)+bt is IDENTICAL to rounds 1-12 — the
// recurrence trajectory must not be perturbed (round-4 lesson).  Bulk store
// emits BOTH bf16 (tail's fp32 target dot) and fp8 (gemm A operand).
// NOTE (round-9): no cross-block producer/consumer sync — device-scope
// fences force L2 writeback/invalidate (5.6x regression).
// ---------------------------------------------------------------------------
__global__ __launch_bounds__(256) void setup_kernel(const int* __restrict__ zi,
                                                    const float* __restrict__ latent,
                                                    const float* __restrict__ Wt,
                                                    const float* __restrict__ bt,
                                                    const float* __restrict__ Wv,
                                                    const float* __restrict__ bv,
                                                    unsigned short* __restrict__ zsb,
                                                    unsigned char* __restrict__ zsa8,
                                                    unsigned char* __restrict__ wv8,
                                                    float* __restrict__ bvs,
                                                    float* __restrict__ S) {
    if (blockIdx.x >= NBATCH) {
        const int cb = blockIdx.x - NBATCH;
        if (cb == 0) {                      // zero the S accumulator
#pragma unroll
            for (int i = 0; i < MROWS / 256; i++)
                S[i * 256 + threadIdx.x] = 0.f;
        }
        if (cb == 1) {                      // zero fp8 pad rows of wv8
            const int base  = VDIM * EMBED / 4;          // first pad uint
            const int npad  = (VPAD - VDIM) * EMBED / 4; // 1504 uints
            for (int i = threadIdx.x; i < npad; i += 256)
                reinterpret_cast<unsigned int*>(wv8)[base + i] = 0u;
        }
        const int idx = cb * 256 + threadIdx.x;
        if (idx < VPAD)                     // prescaled, padded bias
            bvs[idx] = (idx < VDIM) ? bv[idx] * LOG2E : -1e30f;
        if (idx < CONV_N4) {
            float4 v = reinterpret_cast<const float4*>(Wv)[idx];
            int p = pk_fp8<false>(v.x, v.y, 0);
            p = pk_fp8<true>(v.z, v.w, p);
            reinterpret_cast<unsigned int*>(wv8)[idx] = (unsigned int)p;
        }
        return;
    }

    // ---- scan path: one block per batch element ----
    __shared__ float zbuf[2][EMBED];
    __shared__ unsigned short zstash[TSTEPS * EMBED];   // 32 KB bf16 stash
    const int b = blockIdx.x;
    const int e = threadIdx.x >> 1;     // output element 0..127
    const int h = threadIdx.x & 1;      // k-half

    // cache Wt[e][h*64 .. h*64+63] in registers (64 VGPRs)
    float4 wrow[16];
    const float4* wt4 = reinterpret_cast<const float4*>(Wt + e * EMBED + h * 64);
#pragma unroll
    for (int i = 0; i < 16; i++) wrow[i] = wt4[i];
    const float bte = bt[e];

    if (h == 0) zbuf[0][e] = latent[zi[b] * EMBED + e];
    __syncthreads();

    int cur = 0;
    for (int t = 0; t < TSTEPS; t++) {
        const float zc = zbuf[cur][e];      // lane pairs broadcast
        if (h == 0)                         // stash pre-update z (bf16 * log2e)
            zstash[t * EMBED + e] = f2bf_raw(zc * LOG2E);

        // half-dot over k in [h*64, h*64+64)
        const float4* z4 = reinterpret_cast<const float4*>(&zbuf[cur][h * 64]);
        float4 acc = {0.f, 0.f, 0.f, 0.f};
#pragma unroll
        for (int i = 0; i < 16; i++) {
            float4 zv = z4[i];
            acc.x += zv.x * wrow[i].x;
            acc.y += zv.y * wrow[i].y;
            acc.z += zv.z * wrow[i].z;
            acc.w += zv.w * wrow[i].w;
        }
        float v = acc.x + acc.y + acc.z + acc.w;
        float p = __shfl_xor(v, 1);         // partner half (same e, other h)
        float sA = h ? p : v;
        float sB = h ? v : p;
        // summation order identical to rounds 1-12 (same dot trajectory)
        float znew = fast_tanh_nr(((zc + sA) + sB) + bte);
        if (h == 0) zbuf[cur ^ 1][e] = znew;
        __syncthreads();                    // lgkmcnt-only drain (no stores)
        cur ^= 1;
    }

    // bulk store: bf16 copy (tail) + fp8 conversion (gemm A), coalesced
    uint4* dstb = reinterpret_cast<uint4*>(zsb + (long)b * TSTEPS * EMBED);
    uint2* dsta = reinterpret_cast<uint2*>(zsa8 + (long)b * TSTEPS * EMBED);
    const uint4* src = reinterpret_cast<const uint4*>(zstash);
    for (int i = threadIdx.x; i < TSTEPS * EMBED / 8; i += 256) {
        uint4 w = src[i];                   // 8 bf16 (z * log2e)
        dstb[i] = w;
        float f0 = bf_raw2f(w.x & 0xffff), f1 = bf_raw2f(w.x >> 16);
        float f2 = bf_raw2f(w.y & 0xffff), f3 = bf_raw2f(w.y >> 16);
        float f4 = bf_raw2f(w.z & 0xffff), f5 = bf_raw2f(w.z >> 16);
        float f6 = bf_raw2f(w.w & 0xffff), f7 = bf_raw2f(w.w >> 16);
        int lo = pk_fp8<false>(f0, f1, 0); lo = pk_fp8<true>(f2, f3, lo);
        int hi = pk_fp8<false>(f4, f5, 0); hi = pk_fp8<true>(f6, f7, hi);
        uint2 o; o.x = (unsigned int)lo; o.y = (unsigned int)hi;
        dsta[i] = o;
    }
}

// ---------------------------------------------------------------------------
// K1: fused GEMM + sum-of-exp2, fp8 operands.
// R17: grid 131x16 + plain __launch_bounds__(256) + "#pragma unroll 1" on the
// group loop.  History of this residency fix:
//   R14: grid 64x16 -> only 4 blocks/CU (grid-limited), occ 30%, 63us.
//   R15: added ,8 launch-bounds -> VGPR capped 64, scratch spill, 392us.
//   R16: grid 131x16 alone -> MAXGRP=6 made the trip count a compile-time
//        constant, full unroll ballooned VGPR 60->136, occ 10%, 135us.
// The rolled loop at ~60 VGPR is what R14 measured; unroll-1 pins that
// codegen while the 2096-block grid provides 8 blocks/CU of residency.
// Structure otherwise R7/R14-verbatim: 4 waves x 64 rows = 256 rows x 6
// groups of 64 N-cols, double-buffered LDS, one barrier per group, LDS bias
// slice, zero-C init, sums = fma(exp2(d), exp2(bias), sums).
// fp8 LDS layout (16B granule, XOR-8 swizzle): phys granule G' = G ^ (r&7);
// fragment ds_read_b64 at r*128 + ((q>>1)^(r&7))*16 + (q&1)*8 -> 16 lanes
// per quad hit distinct bank pairs (free 2-way only).
// A/B fragment (fp8 16x16x32): lane holds [m|n = lane&15][k = quad*8+j],
// j=0..7 packed LSB-first in one i64.  D: row=(lane>>4)*4+r, col=lane&15.
// ---------------------------------------------------------------------------
typedef __attribute__((ext_vector_type(4))) float f32x4;

__global__ __launch_bounds__(256) void gemm_lse_kernel(const unsigned char* __restrict__ zsa8,
                                                       const unsigned char* __restrict__ wv8,
                                                       const float* __restrict__ bvs,
                                                       float* __restrict__ S) {
    __shared__ unsigned char ldsb[2][8192];  // 2 x 8 KB fp8 B tiles
    __shared__ float ldsbias[MAXGRP * 64];   // this block's bias slice (1.5 KB)

    const int lane  = threadIdx.x & 63;
    const int wave  = threadIdx.x >> 6;
    const int col16 = lane & 15;
    const int quad  = lane >> 4;
    const int mbase = blockIdx.y * 256 + wave * 64;

    // group range for this x-block: exact 6 groups each (786 = 131*6)
    const int x  = blockIdx.x;
    const int g0 = x * MAXGRP;
    const int g1 = g0 + MAXGRP;
    const int nbias = MAXGRP * 64;

    // prologue: stage this block's bias slice into LDS
    for (int i = threadIdx.x; i < nbias; i += 256)
        ldsbias[i] = bvs[g0 * 64 + i];

    // A fragments: 4 M-subtiles x 4 K-chunks, one i64 each (32 VGPRs)
    unsigned long long a[4][4];
#pragma unroll
    for (int s = 0; s < 4; s++)
#pragma unroll
        for (int c = 0; c < 4; c++)
            a[s][c] = *reinterpret_cast<const unsigned long long*>(
                zsa8 + (long)(mbase + s * 16 + col16) * EMBED + c * 32 + quad * 8);

    float sums[16];
#pragma unroll
    for (int i = 0; i < 16; i++) sums[i] = 0.f;

    // stage group g's 8 KB fp8 B-tile into ldsb[buf] (XOR-8 swizzle)
    auto stage = [&](int buf, int g) {
#pragma unroll
        for (int j = 0; j < 2; j++) {
            const int rr = (wave * 2 + j) * 8 + (lane >> 3);   // B-row 0..63
            const int G  = (lane & 7) ^ (rr & 7);              // logical granule
            const unsigned char* gp = wv8 + (long)(g * 64 + rr) * EMBED + G * 16;
            __builtin_amdgcn_global_load_lds(
                (const __attribute__((address_space(1))) void*)gp,
                (__attribute__((address_space(3))) void*)&ldsb[buf][(wave * 2 + j) * 1024],
                16, 0, 0);
        }
    };

    int cur = 0;
    stage(0, g0);

    const f32x4 dzero = {0.f, 0.f, 0.f, 0.f};

#pragma unroll 1   // R17: keep the loop ROLLED — full unroll (R16) bloats
                   // VGPR 60->136 and drops residency to 2 waves/SIMD.
    for (int g = g0; g < g1; g++) {
        __syncthreads();                     // buf[cur] + bias staged; prev reads done
        if (g + 1 < g1) stage(cur ^ 1, g + 1);

        const float* biasg = &ldsbias[(g - g0) * 64];

#pragma unroll
        for (int c = 0; c < 4; c++) {
            // fragment reads: row r = c*16+col16; byte offset q_abs*8
            // (q_abs = kc*4+quad); phys = ((q_abs>>1)^(r&7))*16 + (q_abs&1)*8
            const unsigned char* rowp = &ldsb[cur][(c * 16 + col16) * 128];
            const int r7 = col16 & 7;
            unsigned long long bf[4];
#pragma unroll
            for (int kc = 0; kc < 4; kc++) {
                const int q_abs = kc * 4 + quad;
                bf[kc] = *reinterpret_cast<const unsigned long long*>(
                    rowp + (((q_abs >> 1) ^ r7) * 16) + ((q_abs & 1) * 8));
            }

            const float eb = fast_exp2(biasg[c * 16 + col16]);  // 0 for pad

            // kc-outer, s-inner: consecutive MFMAs are independent (4 chains)
            f32x4 d[4];
#pragma unroll
            for (int s = 0; s < 4; s++)
                d[s] = __builtin_amdgcn_mfma_f32_16x16x32_fp8_fp8(
                    (long long)a[s][0], (long long)bf[0], dzero, 0, 0, 0);
#pragma unroll
            for (int kc = 1; kc < 4; kc++)
#pragma unroll
                for (int s = 0; s < 4; s++)
                    d[s] = __builtin_amdgcn_mfma_f32_16x16x32_fp8_fp8(
                        (long long)a[s][kc], (long long)bf[kc], d[s], 0, 0, 0);

#pragma unroll
            for (int s = 0; s < 4; s++)
#pragma unroll
                for (int r = 0; r < 4; r++)
                    sums[s * 4 + r] = fmaf(fast_exp2(d[s][r]), eb, sums[s * 4 + r]);
        }
        cur ^= 1;
    }

    // reduce partial sums over the 16 columns, one atomic per row per block
#pragma unroll
    for (int s = 0; s < 4; s++) {
#pragma unroll
        for (int r = 0; r < 4; r++) {
            float v = sums[s * 4 + r];
            v += __shfl_xor(v, 1);
            v += __shfl_xor(v, 2);
            v += __shfl_xor(v, 4);
            v += __shfl_xor(v, 8);
            if (col16 == 0)
                atomicAdd(&S[mbase + s * 16 + quad * 4 + r], v);
        }
    }
}

// ---------------------------------------------------------------------------
// K2: yp[row] = ln2*(dot_scaled - log2(S[row])) + bv[y[row]], where
// dot_scaled = (bf16 zsb row) . (fp32 Wv[y] row)  -- zsb is z*log2e in bf16;
// bf16 quantization adds only ~1e-3 to the target dot.
// One wave per row; lane l handles elements {2l, 2l+1}.
// ---------------------------------------------------------------------------
__global__ __launch_bounds__(256) void tail_kernel(const unsigned short* __restrict__ zsb,
                                                   const float* __restrict__ Wv,
                                                   const float* __restrict__ bv,
                                                   const int* __restrict__ y,
                                                   const float* __restrict__ S,
                                                   float* __restrict__ out) {
    const int row  = blockIdx.x * 4 + (threadIdx.x >> 6);
    const int lane = threadIdx.x & 63;
    const int yv = y[row];
    const ushort2* zr = reinterpret_cast<const ushort2*>(zsb + (long)row * EMBED);
    const float2*  wr = reinterpret_cast<const float2*>(Wv + (long)yv * EMBED);
    ushort2 z2 = zr[lane];
    float2  w2 = wr[lane];
    float v = bf_raw2f(z2.x) * w2.x + bf_raw2f(z2.y) * w2.y;
    v += __shfl_xor(v, 32);
    v += __shfl_xor(v, 16);
    v += __shfl_xor(v, 8);
    v += __shfl_xor(v, 4);
    v += __shfl_xor(v, 2);
    v += __shfl_xor(v, 1);
    if (lane == 0)
        out[row] = LN2 * (v - fast_log2(S[row])) + bv[yv];
}

// ---------------------------------------------------------------------------
extern "C" void kernel_launch(void* const* d_in, const int* in_sizes, int n_in,
                              void* d_out, int out_size, void* d_ws, size_t ws_size,
                              hipStream_t stream) {
    const int*   zi     = (const int*)d_in[0];
    const int*   y      = (const int*)d_in[1];
    const float* latent = (const float*)d_in[2];
    const float* Wt     = (const float*)d_in[3];
    const float* bt     = (const float*)d_in[4];
    const float* Wv     = (const float*)d_in[5];
    const float* bv     = (const float*)d_in[6];
    float* out = (float*)d_out;

    char* ws = (char*)d_ws;
    // workspace layout (~8.3 MB total):
    unsigned short* zsb  = (unsigned short*)ws;                        // 1 MB   @ 0
    unsigned char*  zsa8 = (unsigned char*)(ws + (1u << 20));          // 0.5 MB @ 1M
    float*          S    = (float*)(ws + 1536u * 1024);                // 16 KB  @ 1.5M
    float*          bvs  = (float*)(ws + 1536u * 1024 + (64u << 10));  // 197 KB @ 1.5M+64K
    unsigned char*  wv8  = (unsigned char*)(ws + (2u << 20));          // 6.14MB @ 2M

    setup_kernel<<<NBATCH + CONV_BLOCKS, 256, 0, stream>>>(zi, latent, Wt, bt, Wv, bv,
                                                           zsb, zsa8, wv8, bvs, S);

    gemm_lse_kernel<<<dim3(GRIDX, GRIDY), 256, 0, stream>>>(zsa8, wv8, bvs, S);

    tail_kernel<<<MROWS / 4, 256, 0, stream>>>(zsb, Wv, bv, y, S, out);
}

// Round 4
// 197.847 us; speedup vs baseline: 2.6004x; 1.0604x over previous
//
#include <hip/hip_runtime.h>
#include <hip/hip_bf16.h>
#include <hip/hip_fp8.h>

#define EMBED 128
#define TSTEPS 128
#define NBATCH 32
#define VDIM 50257
#define VPAD 50304            // 786 groups * 64 cols
#define MROWS 4096            // NBATCH * TSTEPS
#define NGROUPS 786           // VPAD / 64
#define GRIDX 64              // R18: revert to R14 — 64 ≡ 0 (mod 8 XCDs) so the 16
                              // y-blocks sharing a wv8 slice land on ONE XCD (L2 reuse).
                              // 131 (R17) scattered them -> FETCH 5.3->54MB, dur +13us.
#define GRIDY 16              // 256-row M slices
#define MAXGRP 13             // max groups per x-block: 786 = 64*12 + 18 (ragged)
#define CONV_N4 ((VDIM * EMBED) / 4)          // 1608224 float4 elements
#define CONV_BLOCKS ((CONV_N4 + 255) / 256)   // 6283

static constexpr float LOG2E = 1.4426950408889634f;
static constexpr float LN2   = 0.6931471805599453f;

__device__ __forceinline__ float fast_exp2(float x) {
#if __has_builtin(__builtin_amdgcn_exp2f)
    return __builtin_amdgcn_exp2f(x);
#else
    return exp2f(x);
#endif
}
__device__ __forceinline__ float fast_log2(float x) {
#if __has_builtin(__builtin_amdgcn_logf)
    return __builtin_amdgcn_logf(x);
#else
    return log2f(x);
#endif
}
__device__ __forceinline__ float fast_rcp(float x) {
#if __has_builtin(__builtin_amdgcn_rcpf)
    return __builtin_amdgcn_rcpf(x);
#else
    return 1.0f / x;
#endif
}
// Branch-free tanh with Newton-refined reciprocal (R12-verified: absmax
// 0.1875 vs libm's 0.125, saved ~8us total by avoiding libm's divergent
// poly/exp paths in the scan).
__device__ __forceinline__ float fast_tanh_nr(float x) {
    x = fminf(20.0f, fmaxf(-20.0f, x));
    float t = fast_exp2((2.0f * LOG2E) * x);    // e^{2x}
    float u = t + 1.0f;
    float r = fast_rcp(u);
    r = r * fmaf(-u, r, 2.0f);                  // Newton: error ~ulp^2
    return (t - 1.0f) * r;
}
__device__ __forceinline__ unsigned short f2bf_raw(float f) {
    __hip_bfloat16 h = __float2bfloat16(f);
    union { __hip_bfloat16 b; unsigned short u; } cvt;
    cvt.b = h;
    return cvt.u;
}
__device__ __forceinline__ float bf_raw2f(unsigned short u) {
    union { unsigned int u; float f; } cvt;
    cvt.u = ((unsigned int)u) << 16;
    return cvt.f;
}
// pack 2 floats -> 2 fp8 e4m3 bytes into the selected half of `old`.
// R13 compile fix: the word-select operand of cvt_pk_fp8 must be an ICE,
// so HI is a template parameter (constant inside the body).
template <bool HI>
__device__ __forceinline__ int pk_fp8(float a, float b, int old) {
#if __has_builtin(__builtin_amdgcn_cvt_pk_fp8_f32)
    return __builtin_amdgcn_cvt_pk_fp8_f32(a, b, old, HI);
#else
    __hip_fp8_e4m3 x(a), y(b);
    int v = (int)(unsigned char)x.__x | ((int)(unsigned char)y.__x << 8);
    return HI ? ((old & 0xffff) | (v << 16)) : ((old & ~0xffff) | v);
#endif
}

// ---------------------------------------------------------------------------
// K0 (fused setup): blocks [0,32) = sequential scan (one batch chain each);
// blocks [32, 32+CONV_BLOCKS) convert Wv fp32 -> fp8 e4m3 (+ zero pad rows),
// build bvs[j] = bv[j]*log2e (pad -> -1e30), and zero S.
//
// Scan = R12-verified structure (e = tid>>1, h = tid&1, one shfl_xor,
// ping-pong z, ONE barrier/step, fast_tanh_nr, 32 KB LDS stash).  The fp32
// summation order ((zc+sA)+sB)+bt is IDENTICAL to rounds 1-12 — the
// recurrence trajectory must not be perturbed (round-4 lesson).  Bulk store
// emits BOTH bf16 (tail's fp32 target dot) and fp8 (gemm A operand).
// NOTE (round-9): no cross-block producer/consumer sync — device-scope
// fences force L2 writeback/invalidate (5.6x regression).
// R18: scan waves run at s_setprio(3).  The 32 scan blocks (128 serial
// barrier-steps, latency-critical) share CUs with ~3 conversion blocks each;
// conversion waves' issue traffic lengthens the scan's dependency chain.
// Priority makes scan waves win every issue conflict (T5 regime: waves at
// different phases on one SIMD).  Conversion path stays at prio 0.
// ---------------------------------------------------------------------------
__global__ __launch_bounds__(256) void setup_kernel(const int* __restrict__ zi,
                                                    const float* __restrict__ latent,
                                                    const float* __restrict__ Wt,
                                                    const float* __restrict__ bt,
                                                    const float* __restrict__ Wv,
                                                    const float* __restrict__ bv,
                                                    unsigned short* __restrict__ zsb,
                                                    unsigned char* __restrict__ zsa8,
                                                    unsigned char* __restrict__ wv8,
                                                    float* __restrict__ bvs,
                                                    float* __restrict__ S) {
    if (blockIdx.x >= NBATCH) {
        const int cb = blockIdx.x - NBATCH;
        if (cb == 0) {                      // zero the S accumulator
#pragma unroll
            for (int i = 0; i < MROWS / 256; i++)
                S[i * 256 + threadIdx.x] = 0.f;
        }
        if (cb == 1) {                      // zero fp8 pad rows of wv8
            const int base  = VDIM * EMBED / 4;          // first pad uint
            const int npad  = (VPAD - VDIM) * EMBED / 4; // 1504 uints
            for (int i = threadIdx.x; i < npad; i += 256)
                reinterpret_cast<unsigned int*>(wv8)[base + i] = 0u;
        }
        const int idx = cb * 256 + threadIdx.x;
        if (idx < VPAD)                     // prescaled, padded bias
            bvs[idx] = (idx < VDIM) ? bv[idx] * LOG2E : -1e30f;
        if (idx < CONV_N4) {
            float4 v = reinterpret_cast<const float4*>(Wv)[idx];
            int p = pk_fp8<false>(v.x, v.y, 0);
            p = pk_fp8<true>(v.z, v.w, p);
            reinterpret_cast<unsigned int*>(wv8)[idx] = (unsigned int)p;
        }
        return;
    }

    // ---- scan path: one block per batch element ----
    __builtin_amdgcn_s_setprio(3);          // R18: win issue arbitration vs
                                            // co-resident conversion waves
    __shared__ float zbuf[2][EMBED];
    __shared__ unsigned short zstash[TSTEPS * EMBED];   // 32 KB bf16 stash
    const int b = blockIdx.x;
    const int e = threadIdx.x >> 1;     // output element 0..127
    const int h = threadIdx.x & 1;      // k-half

    // cache Wt[e][h*64 .. h*64+63] in registers (64 VGPRs)
    float4 wrow[16];
    const float4* wt4 = reinterpret_cast<const float4*>(Wt + e * EMBED + h * 64);
#pragma unroll
    for (int i = 0; i < 16; i++) wrow[i] = wt4[i];
    const float bte = bt[e];

    if (h == 0) zbuf[0][e] = latent[zi[b] * EMBED + e];
    __syncthreads();

    int cur = 0;
    for (int t = 0; t < TSTEPS; t++) {
        const float zc = zbuf[cur][e];      // lane pairs broadcast
        if (h == 0)                         // stash pre-update z (bf16 * log2e)
            zstash[t * EMBED + e] = f2bf_raw(zc * LOG2E);

        // half-dot over k in [h*64, h*64+64)
        const float4* z4 = reinterpret_cast<const float4*>(&zbuf[cur][h * 64]);
        float4 acc = {0.f, 0.f, 0.f, 0.f};
#pragma unroll
        for (int i = 0; i < 16; i++) {
            float4 zv = z4[i];
            acc.x += zv.x * wrow[i].x;
            acc.y += zv.y * wrow[i].y;
            acc.z += zv.z * wrow[i].z;
            acc.w += zv.w * wrow[i].w;
        }
        float v = acc.x + acc.y + acc.z + acc.w;
        float p = __shfl_xor(v, 1);         // partner half (same e, other h)
        float sA = h ? p : v;
        float sB = h ? v : p;
        // summation order identical to rounds 1-12 (same dot trajectory)
        float znew = fast_tanh_nr(((zc + sA) + sB) + bte);
        if (h == 0) zbuf[cur ^ 1][e] = znew;
        __syncthreads();                    // lgkmcnt-only drain (no stores)
        cur ^= 1;
    }

    // bulk store: bf16 copy (tail) + fp8 conversion (gemm A), coalesced
    __builtin_amdgcn_s_setprio(0);
    uint4* dstb = reinterpret_cast<uint4*>(zsb + (long)b * TSTEPS * EMBED);
    uint2* dsta = reinterpret_cast<uint2*>(zsa8 + (long)b * TSTEPS * EMBED);
    const uint4* src = reinterpret_cast<const uint4*>(zstash);
    for (int i = threadIdx.x; i < TSTEPS * EMBED / 8; i += 256) {
        uint4 w = src[i];                   // 8 bf16 (z * log2e)
        dstb[i] = w;
        float f0 = bf_raw2f(w.x & 0xffff), f1 = bf_raw2f(w.x >> 16);
        float f2 = bf_raw2f(w.y & 0xffff), f3 = bf_raw2f(w.y >> 16);
        float f4 = bf_raw2f(w.z & 0xffff), f5 = bf_raw2f(w.z >> 16);
        float f6 = bf_raw2f(w.w & 0xffff), f7 = bf_raw2f(w.w >> 16);
        int lo = pk_fp8<false>(f0, f1, 0); lo = pk_fp8<true>(f2, f3, lo);
        int hi = pk_fp8<false>(f4, f5, 0); hi = pk_fp8<true>(f6, f7, hi);
        uint2 o; o.x = (unsigned int)lo; o.y = (unsigned int)hi;
        dsta[i] = o;
    }
}

// ---------------------------------------------------------------------------
// K1: fused GEMM + sum-of-exp2, fp8 operands — R14-VERBATIM (63.4us proven).
// R15-R17 post-mortems, kept as guard rails:
//   R15: __launch_bounds__(256,8) -> VGPR cap 64 -> scratch spill (392us).
//   R16: constant trip count 6 -> full unroll -> VGPR 136, occ 10% (135us).
//   R17: GRIDX=131 (odd mod 8) -> y-sharing blocks scatter across XCDs ->
//        wv8 L2 reuse lost, FETCH 5.3->54MB (76.5us).  GRIDX=64 keeps the
//        16 y-blocks of one wv8 slice on ONE XCD (64 % 8 == 0).
//   Occupancy is register-structural (~3 waves/SIMD incl. accumulators);
//   grid size does not move it — do not chase residency further.
// Structure: 4 waves x 64 rows = 256 rows x 12-13 groups of 64 N-cols,
// double-buffered LDS, one barrier per group, LDS bias slice, zero-C init,
// sums = fma(exp2(d), exp2(bias), sums).
// fp8 LDS layout (16B granule, XOR-8 swizzle): phys granule G' = G ^ (r&7);
// fragment ds_read_b64 at r*128 + ((q>>1)^(r&7))*16 + (q&1)*8 -> 16 lanes
// per quad hit distinct bank pairs (free 2-way only).
// A/B fragment (fp8 16x16x32): lane holds [m|n = lane&15][k = quad*8+j],
// j=0..7 packed LSB-first in one i64.  D: row=(lane>>4)*4+r, col=lane&15.
// ---------------------------------------------------------------------------
typedef __attribute__((ext_vector_type(4))) float f32x4;

__global__ __launch_bounds__(256) void gemm_lse_kernel(const unsigned char* __restrict__ zsa8,
                                                       const unsigned char* __restrict__ wv8,
                                                       const float* __restrict__ bvs,
                                                       float* __restrict__ S) {
    __shared__ unsigned char ldsb[2][8192];  // 2 x 8 KB fp8 B tiles
    __shared__ float ldsbias[MAXGRP * 64];   // this block's bias slice (3.3 KB)

    const int lane  = threadIdx.x & 63;
    const int wave  = threadIdx.x >> 6;
    const int col16 = lane & 15;
    const int quad  = lane >> 4;
    const int mbase = blockIdx.y * 256 + wave * 64;

    // group range for this x-block: 786 = 64*12 + 18
    const int x  = blockIdx.x;
    const int g0 = x * 12 + min(x, 18);
    const int g1 = g0 + 12 + (x < 18 ? 1 : 0);
    const int nbias = (g1 - g0) * 64;

    // prologue: stage this block's bias slice into LDS
    for (int i = threadIdx.x; i < nbias; i += 256)
        ldsbias[i] = bvs[g0 * 64 + i];

    // A fragments: 4 M-subtiles x 4 K-chunks, one i64 each (32 VGPRs)
    unsigned long long a[4][4];
#pragma unroll
    for (int s = 0; s < 4; s++)
#pragma unroll
        for (int c = 0; c < 4; c++)
            a[s][c] = *reinterpret_cast<const unsigned long long*>(
                zsa8 + (long)(mbase + s * 16 + col16) * EMBED + c * 32 + quad * 8);

    float sums[16];
#pragma unroll
    for (int i = 0; i < 16; i++) sums[i] = 0.f;

    // stage group g's 8 KB fp8 B-tile into ldsb[buf] (XOR-8 swizzle)
    auto stage = [&](int buf, int g) {
#pragma unroll
        for (int j = 0; j < 2; j++) {
            const int rr = (wave * 2 + j) * 8 + (lane >> 3);   // B-row 0..63
            const int G  = (lane & 7) ^ (rr & 7);              // logical granule
            const unsigned char* gp = wv8 + (long)(g * 64 + rr) * EMBED + G * 16;
            __builtin_amdgcn_global_load_lds(
                (const __attribute__((address_space(1))) void*)gp,
                (__attribute__((address_space(3))) void*)&ldsb[buf][(wave * 2 + j) * 1024],
                16, 0, 0);
        }
    };

    int cur = 0;
    stage(0, g0);

    const f32x4 dzero = {0.f, 0.f, 0.f, 0.f};

    for (int g = g0; g < g1; g++) {
        __syncthreads();                     // buf[cur] + bias staged; prev reads done
        if (g + 1 < g1) stage(cur ^ 1, g + 1);

        const float* biasg = &ldsbias[(g - g0) * 64];

#pragma unroll
        for (int c = 0; c < 4; c++) {
            // fragment reads: row r = c*16+col16; byte offset q_abs*8
            // (q_abs = kc*4+quad); phys = ((q_abs>>1)^(r&7))*16 + (q_abs&1)*8
            const unsigned char* rowp = &ldsb[cur][(c * 16 + col16) * 128];
            const int r7 = col16 & 7;
            unsigned long long bf[4];
#pragma unroll
            for (int kc = 0; kc < 4; kc++) {
                const int q_abs = kc * 4 + quad;
                bf[kc] = *reinterpret_cast<const unsigned long long*>(
                    rowp + (((q_abs >> 1) ^ r7) * 16) + ((q_abs & 1) * 8));
            }

            const float eb = fast_exp2(biasg[c * 16 + col16]);  // 0 for pad

            // kc-outer, s-inner: consecutive MFMAs are independent (4 chains)
            f32x4 d[4];
#pragma unroll
            for (int s = 0; s < 4; s++)
                d[s] = __builtin_amdgcn_mfma_f32_16x16x32_fp8_fp8(
                    (long long)a[s][0], (long long)bf[0], dzero, 0, 0, 0);
#pragma unroll
            for (int kc = 1; kc < 4; kc++)
#pragma unroll
                for (int s = 0; s < 4; s++)
                    d[s] = __builtin_amdgcn_mfma_f32_16x16x32_fp8_fp8(
                        (long long)a[s][kc], (long long)bf[kc], d[s], 0, 0, 0);

#pragma unroll
            for (int s = 0; s < 4; s++)
#pragma unroll
                for (int r = 0; r < 4; r++)
                    sums[s * 4 + r] = fmaf(fast_exp2(d[s][r]), eb, sums[s * 4 + r]);
        }
        cur ^= 1;
    }

    // reduce partial sums over the 16 columns, one atomic per row per block
#pragma unroll
    for (int s = 0; s < 4; s++) {
#pragma unroll
        for (int r = 0; r < 4; r++) {
            float v = sums[s * 4 + r];
            v += __shfl_xor(v, 1);
            v += __shfl_xor(v, 2);
            v += __shfl_xor(v, 4);
            v += __shfl_xor(v, 8);
            if (col16 == 0)
                atomicAdd(&S[mbase + s * 16 + quad * 4 + r], v);
        }
    }
}

// ---------------------------------------------------------------------------
// K2: yp[row] = ln2*(dot_scaled - log2(S[row])) + bv[y[row]], where
// dot_scaled = (bf16 zsb row) . (fp32 Wv[y] row)  -- zsb is z*log2e in bf16;
// bf16 quantization adds only ~1e-3 to the target dot.
// One wave per row; lane l handles elements {2l, 2l+1}.
// ---------------------------------------------------------------------------
__global__ __launch_bounds__(256) void tail_kernel(const unsigned short* __restrict__ zsb,
                                                   const float* __restrict__ Wv,
                                                   const float* __restrict__ bv,
                                                   const int* __restrict__ y,
                                                   const float* __restrict__ S,
                                                   float* __restrict__ out) {
    const int row  = blockIdx.x * 4 + (threadIdx.x >> 6);
    const int lane = threadIdx.x & 63;
    const int yv = y[row];
    const ushort2* zr = reinterpret_cast<const ushort2*>(zsb + (long)row * EMBED);
    const float2*  wr = reinterpret_cast<const float2*>(Wv + (long)yv * EMBED);
    ushort2 z2 = zr[lane];
    float2  w2 = wr[lane];
    float v = bf_raw2f(z2.x) * w2.x + bf_raw2f(z2.y) * w2.y;
    v += __shfl_xor(v, 32);
    v += __shfl_xor(v, 16);
    v += __shfl_xor(v, 8);
    v += __shfl_xor(v, 4);
    v += __shfl_xor(v, 2);
    v += __shfl_xor(v, 1);
    if (lane == 0)
        out[row] = LN2 * (v - fast_log2(S[row])) + bv[yv];
}

// ---------------------------------------------------------------------------
extern "C" void kernel_launch(void* const* d_in, const int* in_sizes, int n_in,
                              void* d_out, int out_size, void* d_ws, size_t ws_size,
                              hipStream_t stream) {
    const int*   zi     = (const int*)d_in[0];
    const int*   y      = (const int*)d_in[1];
    const float* latent = (const float*)d_in[2];
    const float* Wt     = (const float*)d_in[3];
    const float* bt     = (const float*)d_in[4];
    const float* Wv     = (const float*)d_in[5];
    const float* bv     = (const float*)d_in[6];
    float* out = (float*)d_out;

    char* ws = (char*)d_ws;
    // workspace layout (~8.3 MB total):
    unsigned short* zsb  = (unsigned short*)ws;                        // 1 MB   @ 0
    unsigned char*  zsa8 = (unsigned char*)(ws + (1u << 20));          // 0.5 MB @ 1M
    float*          S    = (float*)(ws + 1536u * 1024);                // 16 KB  @ 1.5M
    float*          bvs  = (float*)(ws + 1536u * 1024 + (64u << 10));  // 197 KB @ 1.5M+64K
    unsigned char*  wv8  = (unsigned char*)(ws + (2u << 20));          // 6.14MB @ 2M

    setup_kernel<<<NBATCH + CONV_BLOCKS, 256, 0, stream>>>(zi, latent, Wt, bt, Wv, bv,
                                                           zsb, zsa8, wv8, bvs, S);

    gemm_lse_kernel<<<dim3(GRIDX, GRIDY), 256, 0, stream>>>(zsa8, wv8, bvs, S);

    tail_kernel<<<MROWS / 4, 256, 0, stream>>>(zsb, Wv, bv, y, S, out);
}

// Round 5
// 194.700 us; speedup vs baseline: 2.6424x; 1.0162x over previous
//
#include <hip/hip_runtime.h>
#include <hip/hip_bf16.h>
#include <hip/hip_fp8.h>

#define EMBED 128
#define TSTEPS 128
#define NBATCH 32
#define VDIM 50257
#define VPAD 50304            // 786 groups * 64 cols
#define MROWS 4096            // NBATCH * TSTEPS
#define NGROUPS 786           // VPAD / 64
#define GRIDX 64              // KEEP 64: same-x blocks stride 64 ≡ 0 (mod 8 XCDs) so the
                              // y-blocks sharing a wv8 slice land on ONE XCD (L2 reuse).
                              // 131 (R17) scattered them -> FETCH 5.3->54MB, dur +13us.
#define GRIDY 32              // R19: 128-row M slices -> 2048 blocks = 8 blocks/CU
#define MAXGRP 13             // max groups per x-block: 786 = 64*12 + 18 (ragged = unroll guard)
#define CONV_N4 ((VDIM * EMBED) / 4)          // 1608224 float4 elements
#define CONV_BLOCKS ((CONV_N4 + 255) / 256)   // 6283

static constexpr float LOG2E = 1.4426950408889634f;
static constexpr float LN2   = 0.6931471805599453f;

__device__ __forceinline__ float fast_exp2(float x) {
#if __has_builtin(__builtin_amdgcn_exp2f)
    return __builtin_amdgcn_exp2f(x);
#else
    return exp2f(x);
#endif
}
__device__ __forceinline__ float fast_log2(float x) {
#if __has_builtin(__builtin_amdgcn_logf)
    return __builtin_amdgcn_logf(x);
#else
    return log2f(x);
#endif
}
__device__ __forceinline__ float fast_rcp(float x) {
#if __has_builtin(__builtin_amdgcn_rcpf)
    return __builtin_amdgcn_rcpf(x);
#else
    return 1.0f / x;
#endif
}
// Branch-free tanh with Newton-refined reciprocal (R12-verified: absmax
// 0.1875 vs libm's 0.125, saved ~8us total by avoiding libm's divergent
// poly/exp paths in the scan).
__device__ __forceinline__ float fast_tanh_nr(float x) {
    x = fminf(20.0f, fmaxf(-20.0f, x));
    float t = fast_exp2((2.0f * LOG2E) * x);    // e^{2x}
    float u = t + 1.0f;
    float r = fast_rcp(u);
    r = r * fmaf(-u, r, 2.0f);                  // Newton: error ~ulp^2
    return (t - 1.0f) * r;
}
__device__ __forceinline__ unsigned short f2bf_raw(float f) {
    __hip_bfloat16 h = __float2bfloat16(f);
    union { __hip_bfloat16 b; unsigned short u; } cvt;
    cvt.b = h;
    return cvt.u;
}
__device__ __forceinline__ float bf_raw2f(unsigned short u) {
    union { unsigned int u; float f; } cvt;
    cvt.u = ((unsigned int)u) << 16;
    return cvt.f;
}
// pack 2 floats -> 2 fp8 e4m3 bytes into the selected half of `old`.
// R13 compile fix: the word-select operand of cvt_pk_fp8 must be an ICE,
// so HI is a template parameter (constant inside the body).
template <bool HI>
__device__ __forceinline__ int pk_fp8(float a, float b, int old) {
#if __has_builtin(__builtin_amdgcn_cvt_pk_fp8_f32)
    return __builtin_amdgcn_cvt_pk_fp8_f32(a, b, old, HI);
#else
    __hip_fp8_e4m3 x(a), y(b);
    int v = (int)(unsigned char)x.__x | ((int)(unsigned char)y.__x << 8);
    return HI ? ((old & 0xffff) | (v << 16)) : ((old & ~0xffff) | v);
#endif
}

// ---------------------------------------------------------------------------
// K0 (fused setup): blocks [0,32) = sequential scan (one batch chain each);
// blocks [32, 32+CONV_BLOCKS) convert Wv fp32 -> fp8 e4m3 (+ zero pad rows),
// build bvs[j] = bv[j]*log2e (pad -> -1e30), and zero S.
//
// Scan = R12-verified structure (e = tid>>1, h = tid&1, one shfl_xor,
// ping-pong z, ONE barrier/step, fast_tanh_nr, 32 KB LDS stash).  The fp32
// summation order ((zc+sA)+sB)+bt is IDENTICAL to rounds 1-12 — the
// recurrence trajectory must not be perturbed (round-4 lesson).  Bulk store
// emits BOTH bf16 (tail's fp32 target dot) and fp8 (gemm A operand).
// NOTE (round-9): no cross-block producer/consumer sync — device-scope
// fences force L2 writeback/invalidate (5.6x regression).
// R18 post-mortem: s_setprio(3) on the scan was NEUTRAL (conversion drains
// in ~15us; scan runs alone after) — reverted to R0-exact.
// ---------------------------------------------------------------------------
__global__ __launch_bounds__(256) void setup_kernel(const int* __restrict__ zi,
                                                    const float* __restrict__ latent,
                                                    const float* __restrict__ Wt,
                                                    const float* __restrict__ bt,
                                                    const float* __restrict__ Wv,
                                                    const float* __restrict__ bv,
                                                    unsigned short* __restrict__ zsb,
                                                    unsigned char* __restrict__ zsa8,
                                                    unsigned char* __restrict__ wv8,
                                                    float* __restrict__ bvs,
                                                    float* __restrict__ S) {
    if (blockIdx.x >= NBATCH) {
        const int cb = blockIdx.x - NBATCH;
        if (cb == 0) {                      // zero the S accumulator
#pragma unroll
            for (int i = 0; i < MROWS / 256; i++)
                S[i * 256 + threadIdx.x] = 0.f;
        }
        if (cb == 1) {                      // zero fp8 pad rows of wv8
            const int base  = VDIM * EMBED / 4;          // first pad uint
            const int npad  = (VPAD - VDIM) * EMBED / 4; // 1504 uints
            for (int i = threadIdx.x; i < npad; i += 256)
                reinterpret_cast<unsigned int*>(wv8)[base + i] = 0u;
        }
        const int idx = cb * 256 + threadIdx.x;
        if (idx < VPAD)                     // prescaled, padded bias
            bvs[idx] = (idx < VDIM) ? bv[idx] * LOG2E : -1e30f;
        if (idx < CONV_N4) {
            float4 v = reinterpret_cast<const float4*>(Wv)[idx];
            int p = pk_fp8<false>(v.x, v.y, 0);
            p = pk_fp8<true>(v.z, v.w, p);
            reinterpret_cast<unsigned int*>(wv8)[idx] = (unsigned int)p;
        }
        return;
    }

    // ---- scan path: one block per batch element ----
    __shared__ float zbuf[2][EMBED];
    __shared__ unsigned short zstash[TSTEPS * EMBED];   // 32 KB bf16 stash
    const int b = blockIdx.x;
    const int e = threadIdx.x >> 1;     // output element 0..127
    const int h = threadIdx.x & 1;      // k-half

    // cache Wt[e][h*64 .. h*64+63] in registers (64 VGPRs)
    float4 wrow[16];
    const float4* wt4 = reinterpret_cast<const float4*>(Wt + e * EMBED + h * 64);
#pragma unroll
    for (int i = 0; i < 16; i++) wrow[i] = wt4[i];
    const float bte = bt[e];

    if (h == 0) zbuf[0][e] = latent[zi[b] * EMBED + e];
    __syncthreads();

    int cur = 0;
    for (int t = 0; t < TSTEPS; t++) {
        const float zc = zbuf[cur][e];      // lane pairs broadcast
        if (h == 0)                         // stash pre-update z (bf16 * log2e)
            zstash[t * EMBED + e] = f2bf_raw(zc * LOG2E);

        // half-dot over k in [h*64, h*64+64)
        const float4* z4 = reinterpret_cast<const float4*>(&zbuf[cur][h * 64]);
        float4 acc = {0.f, 0.f, 0.f, 0.f};
#pragma unroll
        for (int i = 0; i < 16; i++) {
            float4 zv = z4[i];
            acc.x += zv.x * wrow[i].x;
            acc.y += zv.y * wrow[i].y;
            acc.z += zv.z * wrow[i].z;
            acc.w += zv.w * wrow[i].w;
        }
        float v = acc.x + acc.y + acc.z + acc.w;
        float p = __shfl_xor(v, 1);         // partner half (same e, other h)
        float sA = h ? p : v;
        float sB = h ? v : p;
        // summation order identical to rounds 1-12 (same dot trajectory)
        float znew = fast_tanh_nr(((zc + sA) + sB) + bte);
        if (h == 0) zbuf[cur ^ 1][e] = znew;
        __syncthreads();                    // lgkmcnt-only drain (no stores)
        cur ^= 1;
    }

    // bulk store: bf16 copy (tail) + fp8 conversion (gemm A), coalesced
    uint4* dstb = reinterpret_cast<uint4*>(zsb + (long)b * TSTEPS * EMBED);
    uint2* dsta = reinterpret_cast<uint2*>(zsa8 + (long)b * TSTEPS * EMBED);
    const uint4* src = reinterpret_cast<const uint4*>(zstash);
    for (int i = threadIdx.x; i < TSTEPS * EMBED / 8; i += 256) {
        uint4 w = src[i];                   // 8 bf16 (z * log2e)
        dstb[i] = w;
        float f0 = bf_raw2f(w.x & 0xffff), f1 = bf_raw2f(w.x >> 16);
        float f2 = bf_raw2f(w.y & 0xffff), f3 = bf_raw2f(w.y >> 16);
        float f4 = bf_raw2f(w.z & 0xffff), f5 = bf_raw2f(w.z >> 16);
        float f6 = bf_raw2f(w.w & 0xffff), f7 = bf_raw2f(w.w >> 16);
        int lo = pk_fp8<false>(f0, f1, 0); lo = pk_fp8<true>(f2, f3, lo);
        int hi = pk_fp8<false>(f4, f5, 0); hi = pk_fp8<true>(f6, f7, hi);
        uint2 o; o.x = (unsigned int)lo; o.y = (unsigned int)hi;
        dsta[i] = o;
    }
}

// ---------------------------------------------------------------------------
// K1: fused GEMM + sum-of-exp2, fp8 operands.
// R19: GRIDY 16->32 (128-row blocks, wave owns 32 rows: s in {0,1}).
// Why: R18 showed occupancy 32% == exactly the 1024-block grid limit
// (4 blocks/CU); VGPR 56 / LDS 19.3KB allow 8.  Doubling GRIDY doubles
// residency while preserving every guard rail learned in R15-R17:
//   R15: no launch-bounds VGPR cap (spill).      [plain (256) kept]
//   R16: trip count must stay RUNTIME-ragged.    [12/13 split kept]
//   R17: GRIDX must stay 64 (0 mod 8) for XCD-   [GRIDX kept; same-x
//        local wv8 L2 reuse.                      blocks stride 64]
// Total work unchanged: A-bytes, stage-bytes/group, exp2 count, atomic
// count all identical — only waves/CU doubles (m114: wave-level overlap
// covers the per-group barrier drain + MFMA->exp2 epilogue chain).
// Structure: 4 waves x 32 rows = 128 rows x 12-13 groups of 64 N-cols,
// double-buffered LDS, one barrier per group, LDS bias slice, zero-C init,
// sums = fma(exp2(d), exp2(bias), sums).
// fp8 LDS layout (16B granule, XOR-8 swizzle): phys granule G' = G ^ (r&7);
// fragment ds_read_b64 at r*128 + ((q>>1)^(r&7))*16 + (q&1)*8 -> 16 lanes
// per quad hit distinct bank pairs (free 2-way only).
// A/B fragment (fp8 16x16x32): lane holds [m|n = lane&15][k = quad*8+j],
// j=0..7 packed LSB-first in one i64.  D: row=(lane>>4)*4+r, col=lane&15.
// ---------------------------------------------------------------------------
typedef __attribute__((ext_vector_type(4))) float f32x4;

__global__ __launch_bounds__(256) void gemm_lse_kernel(const unsigned char* __restrict__ zsa8,
                                                       const unsigned char* __restrict__ wv8,
                                                       const float* __restrict__ bvs,
                                                       float* __restrict__ S) {
    __shared__ unsigned char ldsb[2][8192];  // 2 x 8 KB fp8 B tiles
    __shared__ float ldsbias[MAXGRP * 64];   // this block's bias slice (3.3 KB)

    const int lane  = threadIdx.x & 63;
    const int wave  = threadIdx.x >> 6;
    const int col16 = lane & 15;
    const int quad  = lane >> 4;
    const int mbase = blockIdx.y * 128 + wave * 32;   // R19: 128-row blocks

    // group range for this x-block: 786 = 64*12 + 18
    const int x  = blockIdx.x;
    const int g0 = x * 12 + min(x, 18);
    const int g1 = g0 + 12 + (x < 18 ? 1 : 0);
    const int nbias = (g1 - g0) * 64;

    // prologue: stage this block's bias slice into LDS
    for (int i = threadIdx.x; i < nbias; i += 256)
        ldsbias[i] = bvs[g0 * 64 + i];

    // A fragments: 2 M-subtiles x 4 K-chunks, one i64 each (16 VGPRs)
    unsigned long long a[2][4];
#pragma unroll
    for (int s = 0; s < 2; s++)
#pragma unroll
        for (int c = 0; c < 4; c++)
            a[s][c] = *reinterpret_cast<const unsigned long long*>(
                zsa8 + (long)(mbase + s * 16 + col16) * EMBED + c * 32 + quad * 8);

    float sums[8];
#pragma unroll
    for (int i = 0; i < 8; i++) sums[i] = 0.f;

    // stage group g's 8 KB fp8 B-tile into ldsb[buf] (XOR-8 swizzle)
    auto stage = [&](int buf, int g) {
#pragma unroll
        for (int j = 0; j < 2; j++) {
            const int rr = (wave * 2 + j) * 8 + (lane >> 3);   // B-row 0..63
            const int G  = (lane & 7) ^ (rr & 7);              // logical granule
            const unsigned char* gp = wv8 + (long)(g * 64 + rr) * EMBED + G * 16;
            __builtin_amdgcn_global_load_lds(
                (const __attribute__((address_space(1))) void*)gp,
                (__attribute__((address_space(3))) void*)&ldsb[buf][(wave * 2 + j) * 1024],
                16, 0, 0);
        }
    };

    int cur = 0;
    stage(0, g0);

    const f32x4 dzero = {0.f, 0.f, 0.f, 0.f};

    for (int g = g0; g < g1; g++) {
        __syncthreads();                     // buf[cur] + bias staged; prev reads done
        if (g + 1 < g1) stage(cur ^ 1, g + 1);

        const float* biasg = &ldsbias[(g - g0) * 64];

#pragma unroll
        for (int c = 0; c < 4; c++) {
            // fragment reads: row r = c*16+col16; byte offset q_abs*8
            // (q_abs = kc*4+quad); phys = ((q_abs>>1)^(r&7))*16 + (q_abs&1)*8
            const unsigned char* rowp = &ldsb[cur][(c * 16 + col16) * 128];
            const int r7 = col16 & 7;
            unsigned long long bf[4];
#pragma unroll
            for (int kc = 0; kc < 4; kc++) {
                const int q_abs = kc * 4 + quad;
                bf[kc] = *reinterpret_cast<const unsigned long long*>(
                    rowp + (((q_abs >> 1) ^ r7) * 16) + ((q_abs & 1) * 8));
            }

            const float eb = fast_exp2(biasg[c * 16 + col16]);  // 0 for pad

            // kc-outer, s-inner: consecutive MFMAs are independent (2 chains)
            f32x4 d[2];
#pragma unroll
            for (int s = 0; s < 2; s++)
                d[s] = __builtin_amdgcn_mfma_f32_16x16x32_fp8_fp8(
                    (long long)a[s][0], (long long)bf[0], dzero, 0, 0, 0);
#pragma unroll
            for (int kc = 1; kc < 4; kc++)
#pragma unroll
                for (int s = 0; s < 2; s++)
                    d[s] = __builtin_amdgcn_mfma_f32_16x16x32_fp8_fp8(
                        (long long)a[s][kc], (long long)bf[kc], d[s], 0, 0, 0);

#pragma unroll
            for (int s = 0; s < 2; s++)
#pragma unroll
                for (int r = 0; r < 4; r++)
                    sums[s * 4 + r] = fmaf(fast_exp2(d[s][r]), eb, sums[s * 4 + r]);
        }
        cur ^= 1;
    }

    // reduce partial sums over the 16 columns, one atomic per row per block
#pragma unroll
    for (int s = 0; s < 2; s++) {
#pragma unroll
        for (int r = 0; r < 4; r++) {
            float v = sums[s * 4 + r];
            v += __shfl_xor(v, 1);
            v += __shfl_xor(v, 2);
            v += __shfl_xor(v, 4);
            v += __shfl_xor(v, 8);
            if (col16 == 0)
                atomicAdd(&S[mbase + s * 16 + quad * 4 + r], v);
        }
    }
}

// ---------------------------------------------------------------------------
// K2: yp[row] = ln2*(dot_scaled - log2(S[row])) + bv[y[row]], where
// dot_scaled = (bf16 zsb row) . (fp32 Wv[y] row)  -- zsb is z*log2e in bf16;
// bf16 quantization adds only ~1e-3 to the target dot.
// One wave per row; lane l handles elements {2l, 2l+1}.
// ---------------------------------------------------------------------------
__global__ __launch_bounds__(256) void tail_kernel(const unsigned short* __restrict__ zsb,
                                                   const float* __restrict__ Wv,
                                                   const float* __restrict__ bv,
                                                   const int* __restrict__ y,
                                                   const float* __restrict__ S,
                                                   float* __restrict__ out) {
    const int row  = blockIdx.x * 4 + (threadIdx.x >> 6);
    const int lane = threadIdx.x & 63;
    const int yv = y[row];
    const ushort2* zr = reinterpret_cast<const ushort2*>(zsb + (long)row * EMBED);
    const float2*  wr = reinterpret_cast<const float2*>(Wv + (long)yv * EMBED);
    ushort2 z2 = zr[lane];
    float2  w2 = wr[lane];
    float v = bf_raw2f(z2.x) * w2.x + bf_raw2f(z2.y) * w2.y;
    v += __shfl_xor(v, 32);
    v += __shfl_xor(v, 16);
    v += __shfl_xor(v, 8);
    v += __shfl_xor(v, 4);
    v += __shfl_xor(v, 2);
    v += __shfl_xor(v, 1);
    if (lane == 0)
        out[row] = LN2 * (v - fast_log2(S[row])) + bv[yv];
}

// ---------------------------------------------------------------------------
extern "C" void kernel_launch(void* const* d_in, const int* in_sizes, int n_in,
                              void* d_out, int out_size, void* d_ws, size_t ws_size,
                              hipStream_t stream) {
    const int*   zi     = (const int*)d_in[0];
    const int*   y      = (const int*)d_in[1];
    const float* latent = (const float*)d_in[2];
    const float* Wt     = (const float*)d_in[3];
    const float* bt     = (const float*)d_in[4];
    const float* Wv     = (const float*)d_in[5];
    const float* bv     = (const float*)d_in[6];
    float* out = (float*)d_out;

    char* ws = (char*)d_ws;
    // workspace layout (~8.3 MB total):
    unsigned short* zsb  = (unsigned short*)ws;                        // 1 MB   @ 0
    unsigned char*  zsa8 = (unsigned char*)(ws + (1u << 20));          // 0.5 MB @ 1M
    float*          S    = (float*)(ws + 1536u * 1024);                // 16 KB  @ 1.5M
    float*          bvs  = (float*)(ws + 1536u * 1024 + (64u << 10));  // 197 KB @ 1.5M+64K
    unsigned char*  wv8  = (unsigned char*)(ws + (2u << 20));          // 6.14MB @ 2M

    setup_kernel<<<NBATCH + CONV_BLOCKS, 256, 0, stream>>>(zi, latent, Wt, bt, Wv, bv,
                                                           zsb, zsa8, wv8, bvs, S);

    gemm_lse_kernel<<<dim3(GRIDX, GRIDY), 256, 0, stream>>>(zsa8, wv8, bvs, S);

    tail_kernel<<<MROWS / 4, 256, 0, stream>>>(zsb, Wv, bv, y, S, out);
}